// Round 12
// baseline (249.637 us; speedup 1.0000x reference)
//
#include <hip/hip_runtime.h>

#define INVB  2.0f      // 1/beta
#define TOL   0.1f
#define EPS   1e-8f
#define NITER 50
#define NP    4         // blocks per graph

// ---------------------------------------------------------------------------
// P=4 blocks per graph, 1024 threads each (512 blocks = 2/CU co-resident;
// VGPR must stay <= 64 for the graph-local spin sync's residency guarantee).
// Block p owns rows [p*128, p*128+128) of its graph. Log-space implicit T:
//   T_k = exp(LD_k[n] + LS_k[m] - k*INVB*C[n,m]),  -inf masks invalid.
// ONE C-pass per iteration: per own row, scan1 computes err_k + b_{k+1};
// then LD_{k+2} is known immediately and scan2 (REGISTER-held row, no L1
// re-read) accumulates the NEXT col sums.
// 1-DEEP ROW PREFETCH, register-lean: only cur(8)+next(8)+fa(8) VGPRs live
// across the wsum chains; LS/lsig vectors are transient LDS re-reads; no
// per-element products persisted (r6/r9/r10 lesson: bigger live sets spill
// -> phantom +470 MB HBM traffic. Tripwire: FETCH/WRITE inflation = spill).
// Per iteration: 1 graph-local 4-block sync (a-partials + err exchange).
// ---------------------------------------------------------------------------

__device__ __forceinline__ float wsum(float v) {
    #pragma unroll
    for (int o = 1; o < 64; o <<= 1) v += __shfl_xor(v, o, 64);
    return v;   // all lanes hold the total
}

__device__ __forceinline__ void group_arrive(unsigned* flagp) {
    __hip_atomic_fetch_add(flagp, 1u, __ATOMIC_RELEASE, __HIP_MEMORY_SCOPE_AGENT);
}
__device__ __forceinline__ void group_wait(unsigned* flagp, unsigned target) {
    long sp = 0;
    while (__hip_atomic_load(flagp, __ATOMIC_RELAXED, __HIP_MEMORY_SCOPE_AGENT)
               < target && sp < (1L << 24)) {
        __builtin_amdgcn_s_sleep(2); ++sp;
    }
    (void)__hip_atomic_load(flagp, __ATOMIC_ACQUIRE, __HIP_MEMORY_SCOPE_AGENT);
}

// ------------- pre-kernel: zero control words + mask dtype detect -----------
__global__ void k_zero(unsigned* ctrl, int ctrlwords, int* mode,
                       const unsigned* mraw, int nwords) {
    const int t = threadIdx.x;
    for (int i = t; i < ctrlwords; i += 1024) ctrl[i] = 0u;
    __shared__ int sF, sB;
    if (t == 0) { sF = 0; sB = 0; }
    __syncthreads();
    int f = 0, b = 0;
    for (int i = t; i < nwords; i += 1024) {
        unsigned w = mraw[i];
        if (w == 0x3f800000u) f = 1;
        else if (w > 1u)      b = 1;
    }
    if (f) atomicOr(&sF, 1);
    if (b) atomicOr(&sB, 1);
    __syncthreads();
    if (t == 0) *mode = sF ? 2 : (sB ? 1 : 0);
}

// ============================ main kernel ===================================
__global__ __launch_bounds__(1024, 8) void k_ipot4(
    const float* __restrict__ C, const void* __restrict__ mraw,
    int bs, int N,
    unsigned* err_u, unsigned* flags, float* dpart, const int* mode_p,
    float* apart, float* outD, float* outT, float* outC)
{
    const int g    = blockIdx.x >> 2;          // graph
    const int p    = blockIdx.x & 3;           // sub-block in graph
    const int t    = threadIdx.x;
    const int lane = t & 63;
    const int wv   = t >> 6;                   // 0..15
    const int NR   = N >> 2;                   // own rows (128)
    const int r0   = p * NR;
    const int rpw  = NR >> 4;                  // rows per wave (8)
    const float NEG = -__builtin_inff();
    unsigned* flagp = &flags[g * 16];

    __shared__ __align__(16) float ls_s[512];    // LS current
    __shared__ __align__(16) float lsp_s[512];   // LS previous
    __shared__ __align__(16) float lsig_s[512];  // log sigma current
    __shared__ __align__(16) float m01[512];     // col mask 0/1
    __shared__ float ld_own[128], ldp_own[128];  // own-row LD cur/prev
    __shared__ __align__(16) float ap_ws[16][512]; // per-wave col partials
    __shared__ float red_s[16];
    __shared__ float muv_s, lmu_s, errg_s;
    __shared__ unsigned errbits_s;

    // ---- init: mask row, count, scalings ----
    {
        const int mode = *mode_p;
        if (t < N) {
            const int idx = g * N + t;
            bool mv;
            if (mode == 1)      mv = ((const unsigned char*)mraw)[idx] != 0;
            else if (mode == 2) mv = ((const float*)mraw)[idx] != 0.0f;
            else                mv = ((const int*)mraw)[idx] != 0;
            m01[t] = mv ? 1.f : 0.f;
            const float z = mv ? 0.f : NEG;
            ls_s[t] = z; lsp_s[t] = z;
        }
        __syncthreads();
        if (t < N) {
            float v = wsum(m01[t]);
            if (lane == 0) red_s[wv] = v;
        }
        __syncthreads();
        if (t == 0) {
            float cnt = 0.f;
            for (int i = 0; i < (N >> 6); ++i) cnt += red_s[i];
            muv_s = 1.0f / cnt;                 // cnt >= 1 by setup
            lmu_s = __logf(muv_s);
        }
        __syncthreads();
        if (t < N) lsig_s[t] = (m01[t] != 0.f) ? lmu_s : NEG;
        if (t < NR) {
            const float z = (m01[r0 + t] != 0.f) ? 0.f : NEG;
            ld_own[t] = z; ldp_own[t] = z;
        }
        __syncthreads();
    }
    const float muv = muv_s, lmu = lmu_s;
    unsigned rnd = 0;

    const float* wrow = C + ((size_t)g * N + r0 + wv * rpw) * N;  // wave's rows
    const int mb0 = lane * 4, mb1 = 256 + lane * 4;

    // ---- pass 0: b0 (own rows) + a0 partials (prefetched, reg-held rows) ----
    {
        float4 fa[2] = {{0,0,0,0},{0,0,0,0}};
        float4 ca = *(const float4*)(wrow + mb0);
        float4 cb = *(const float4*)(wrow + mb1);
        for (int j = 0; j < rpw; ++j) {
            const int jn = (j + 1 < rpw) ? (j + 1) : j;
            const float4 na = *(const float4*)(wrow + (size_t)jn * N + mb0);
            const float4 nb = *(const float4*)(wrow + (size_t)jn * N + mb1);
            const int lo = wv * rpw + j;
            const bool valid = m01[r0 + lo] != 0.f;
            float bacc = 0.f;
            if (valid) {
                float4 m4 = *(const float4*)(&m01[mb0]);
                bacc += m4.x * __expf(lmu - INVB * ca.x);
                bacc += m4.y * __expf(lmu - INVB * ca.y);
                bacc += m4.z * __expf(lmu - INVB * ca.z);
                bacc += m4.w * __expf(lmu - INVB * ca.w);
                m4 = *(const float4*)(&m01[mb1]);
                bacc += m4.x * __expf(lmu - INVB * cb.x);
                bacc += m4.y * __expf(lmu - INVB * cb.y);
                bacc += m4.z * __expf(lmu - INVB * cb.z);
                bacc += m4.w * __expf(lmu - INVB * cb.w);
            }
            bacc = wsum(bacc);
            const float ldn1 = valid ? __logf(muv / bacc) : NEG;  // LD_1
            if (lane == 0) ld_own[lo] = ldn1;
            if (valid) {
                float4 l4 = *(const float4*)(&ls_s[mb0]);
                fa[0].x += __expf(ldn1 + l4.x - INVB * ca.x);
                fa[0].y += __expf(ldn1 + l4.y - INVB * ca.y);
                fa[0].z += __expf(ldn1 + l4.z - INVB * ca.z);
                fa[0].w += __expf(ldn1 + l4.w - INVB * ca.w);
                l4 = *(const float4*)(&ls_s[mb1]);
                fa[1].x += __expf(ldn1 + l4.x - INVB * cb.x);
                fa[1].y += __expf(ldn1 + l4.y - INVB * cb.y);
                fa[1].z += __expf(ldn1 + l4.z - INVB * cb.z);
                fa[1].w += __expf(ldn1 + l4.w - INVB * cb.w);
            }
            ca = na; cb = nb;
        }
        *(float4*)&ap_ws[wv][mb0] = fa[0];
        *(float4*)&ap_ws[wv][mb1] = fa[1];
        __syncthreads();
        if (t < N) {
            float av = 0.f;
            #pragma unroll
            for (int w = 0; w < 16; ++w) av += ap_ws[w][t];
            apart[((size_t)(g * NP + p)) * N + t] = av;
        }
        __syncthreads();
        ++rnd;
        if (t == 0) { group_arrive(flagp); group_wait(flagp, NP * rnd); }
        __syncthreads();
        if (t < N && m01[t] != 0.f) {          // LS_1 / lsig_1 (all identical)
            float av = 0.f;
            #pragma unroll
            for (int q = 0; q < NP; ++q) av += apart[((size_t)(g * NP + q)) * N + t];
            const float lsg = __logf(muv / av);
            lsp_s[t] = ls_s[t]; ls_s[t] += lsg; lsig_s[t] = lsg;
        }
        __syncthreads();
    }

    // ---- iterations: one C-pass each (two-scan, prefetched, reg-held) ----
    int kf = NITER;
    for (int it = 0; it < NITER; ++it) {
        const float s1 = (float)it * INVB;
        const float s2 = s1 + INVB;
        const float s3 = s2 + INVB;
        if (t == 0) errbits_s = 0u;
        float4 fa[2] = {{0,0,0,0},{0,0,0,0}};
        float errmax = 0.f;
        __syncthreads();

        {
            float4 ca = *(const float4*)(wrow + mb0);
            float4 cb = *(const float4*)(wrow + mb1);
            for (int j = 0; j < rpw; ++j) {
                const int jn = (j + 1 < rpw) ? (j + 1) : j;
                const float4 na = *(const float4*)(wrow + (size_t)jn * N + mb0);
                const float4 nb = *(const float4*)(wrow + (size_t)jn * N + mb1);
                const int lo = wv * rpw + j;
                const bool valid = m01[r0 + lo] != 0.f;
                const float ldn = ld_own[lo], ldo = ldp_own[lo];
                float eacc = 0.f, bacc = 0.f;
                if (valid) {
                    float4 ln4 = *(const float4*)(&ls_s[mb0]);
                    float4 lo4 = *(const float4*)(&lsp_s[mb0]);
                    float4 lg4 = *(const float4*)(&lsig_s[mb0]);
                    float tn, to;
                    tn = __expf(ldn + ln4.x - s2 * ca.x);
                    to = __expf(ldo + lo4.x - s1 * ca.x);
                    eacc += fabsf(tn - to);
                    bacc += __expf(ldn + ln4.x + lg4.x - s3 * ca.x);
                    tn = __expf(ldn + ln4.y - s2 * ca.y);
                    to = __expf(ldo + lo4.y - s1 * ca.y);
                    eacc += fabsf(tn - to);
                    bacc += __expf(ldn + ln4.y + lg4.y - s3 * ca.y);
                    tn = __expf(ldn + ln4.z - s2 * ca.z);
                    to = __expf(ldo + lo4.z - s1 * ca.z);
                    eacc += fabsf(tn - to);
                    bacc += __expf(ldn + ln4.z + lg4.z - s3 * ca.z);
                    tn = __expf(ldn + ln4.w - s2 * ca.w);
                    to = __expf(ldo + lo4.w - s1 * ca.w);
                    eacc += fabsf(tn - to);
                    bacc += __expf(ldn + ln4.w + lg4.w - s3 * ca.w);
                    ln4 = *(const float4*)(&ls_s[mb1]);
                    lo4 = *(const float4*)(&lsp_s[mb1]);
                    lg4 = *(const float4*)(&lsig_s[mb1]);
                    tn = __expf(ldn + ln4.x - s2 * cb.x);
                    to = __expf(ldo + lo4.x - s1 * cb.x);
                    eacc += fabsf(tn - to);
                    bacc += __expf(ldn + ln4.x + lg4.x - s3 * cb.x);
                    tn = __expf(ldn + ln4.y - s2 * cb.y);
                    to = __expf(ldo + lo4.y - s1 * cb.y);
                    eacc += fabsf(tn - to);
                    bacc += __expf(ldn + ln4.y + lg4.y - s3 * cb.y);
                    tn = __expf(ldn + ln4.z - s2 * cb.z);
                    to = __expf(ldo + lo4.z - s1 * cb.z);
                    eacc += fabsf(tn - to);
                    bacc += __expf(ldn + ln4.z + lg4.z - s3 * cb.z);
                    tn = __expf(ldn + ln4.w - s2 * cb.w);
                    to = __expf(ldo + lo4.w - s1 * cb.w);
                    eacc += fabsf(tn - to);
                    bacc += __expf(ldn + ln4.w + lg4.w - s3 * cb.w);
                }
                bacc = wsum(bacc);
                eacc = wsum(eacc);
                errmax = fmaxf(errmax, eacc);
                const float ldn2 = valid ? (ldn + __logf(muv / bacc)) : NEG;
                if (lane == 0) { ldp_own[lo] = ldn; ld_own[lo] = ldn2; }
                if (valid) {
                    float4 l4 = *(const float4*)(&ls_s[mb0]);
                    fa[0].x += __expf(ldn2 + l4.x - s3 * ca.x);
                    fa[0].y += __expf(ldn2 + l4.y - s3 * ca.y);
                    fa[0].z += __expf(ldn2 + l4.z - s3 * ca.z);
                    fa[0].w += __expf(ldn2 + l4.w - s3 * ca.w);
                    l4 = *(const float4*)(&ls_s[mb1]);
                    fa[1].x += __expf(ldn2 + l4.x - s3 * cb.x);
                    fa[1].y += __expf(ldn2 + l4.y - s3 * cb.y);
                    fa[1].z += __expf(ldn2 + l4.z - s3 * cb.z);
                    fa[1].w += __expf(ldn2 + l4.w - s3 * cb.w);
                }
                ca = na; cb = nb;
            }
        }
        if (lane == 0) atomicMax(&errbits_s, __float_as_uint(errmax));
        *(float4*)&ap_ws[wv][mb0] = fa[0];
        *(float4*)&ap_ws[wv][mb1] = fa[1];
        __syncthreads();
        if (t < N) {
            float av = 0.f;
            #pragma unroll
            for (int w = 0; w < 16; ++w) av += ap_ws[w][t];
            apart[((size_t)(g * NP + p)) * N + t] = av;
        }
        if (t == 0) atomicMax(&err_u[g * 64 + it], errbits_s);
        __syncthreads();
        ++rnd;
        if (t == 0) {
            group_arrive(flagp); group_wait(flagp, NP * rnd);
            errg_s = __uint_as_float(err_u[g * 64 + it]);
        }
        __syncthreads();
        if (errg_s < TOL) { kf = it + 1; break; }
        if (it == NITER - 1) { kf = NITER; break; }
        if (t < N && m01[t] != 0.f) {          // LS_{k+2}, lsig_{k+2}
            float av = 0.f;
            #pragma unroll
            for (int q = 0; q < NP; ++q) av += apart[((size_t)(g * NP + q)) * N + t];
            const float lsg = __logf(muv / av);
            lsp_s[t] = ls_s[t]; ls_s[t] += lsg; lsig_s[t] = lsg;
        }
        __syncthreads();
    }

    // ---- final: T out + C copy + distance dot (prefetched, reg-held) ----
    float dacc = 0.f;
    {
        const float sF = (float)kf * INVB;
        float4 ca = *(const float4*)(wrow + mb0);
        float4 cb = *(const float4*)(wrow + mb1);
        for (int j = 0; j < rpw; ++j) {
            const int jn = (j + 1 < rpw) ? (j + 1) : j;
            const float4 na = *(const float4*)(wrow + (size_t)jn * N + mb0);
            const float4 nb = *(const float4*)(wrow + (size_t)jn * N + mb1);
            const int lo = wv * rpw + j;
            const int gr = g * N + r0 + lo;
            const float ldv = ldp_own[lo];     // LD_kf (ld_own holds kf+1)
            float4 l4 = *(const float4*)(&ls_s[mb0]);
            float4 t4;
            t4.x = __expf(ldv + l4.x - sF * ca.x);
            t4.y = __expf(ldv + l4.y - sF * ca.y);
            t4.z = __expf(ldv + l4.z - sF * ca.z);
            t4.w = __expf(ldv + l4.w - sF * ca.w);
            dacc += t4.x * ca.x + t4.y * ca.y + t4.z * ca.z + t4.w * ca.w;
            const size_t grN = (size_t)gr * N;
            *(float4*)(outT + grN + mb0) = t4;
            *(float4*)(outC + grN + mb0) = ca;
            l4 = *(const float4*)(&ls_s[mb1]);
            t4.x = __expf(ldv + l4.x - sF * cb.x);
            t4.y = __expf(ldv + l4.y - sF * cb.y);
            t4.z = __expf(ldv + l4.z - sF * cb.z);
            t4.w = __expf(ldv + l4.w - sF * cb.w);
            dacc += t4.x * cb.x + t4.y * cb.y + t4.z * cb.z + t4.w * cb.w;
            *(float4*)(outT + grN + mb1) = t4;
            *(float4*)(outC + grN + mb1) = cb;
            ca = na; cb = nb;
        }
    }
    // block-reduce distance partial
    dacc = wsum(dacc);
    if (lane == 0) red_s[wv] = dacc;
    __syncthreads();
    ++rnd;
    if (t == 0) {
        float d = 0.f;
        #pragma unroll
        for (int w = 0; w < 16; ++w) d += red_s[w];
        dpart[g * NP + p] = d;
        group_arrive(flagp);
        if (p == 0) {
            group_wait(flagp, NP * rnd);
            float dt = 0.f;
            #pragma unroll
            for (int q = 0; q < NP; ++q) dt += dpart[g * NP + q];
            outD[g] = dt;
        }
    }
}

// ---------------------------------------------------------------------------
extern "C" void kernel_launch(void* const* d_in, const int* in_sizes, int n_in,
                              void* d_out, int out_size, void* d_ws, size_t ws_size,
                              hipStream_t stream) {
    const float* C    = (const float*)d_in[0];
    const void*  mask = d_in[4];
    const int R  = in_sizes[4];           // bs*N
    const int N  = in_sizes[0] / R;       // 512
    const int bs = R / N;                 // 128

    unsigned* wsu   = (unsigned*)d_ws;
    unsigned* err_u = wsu;                          // bs*64
    unsigned* flags = wsu + (size_t)bs * 64;        // bs*16
    float*    dpart = (float*)(flags + (size_t)bs * 16);   // bs*NP
    int*      mode  = (int*)(dpart + (size_t)bs * NP);     // 1
    const int ctrlwords = bs * 64 + bs * 16 + bs * NP + 1;
    float*    apart = (float*)(wsu + ((ctrlwords + 255) & ~255)); // bs*NP*N

    float* outD = (float*)d_out;
    float* outT = outD + bs;
    float* outC = outT + (size_t)bs * N * N;

    k_zero<<<1, 1024, 0, stream>>>(wsu, ctrlwords, mode,
                                   (const unsigned*)mask, R / 4);
    k_ipot4<<<bs * NP, 1024, 0, stream>>>(C, mask, bs, N,
                                          err_u, flags, dpart, mode,
                                          apart, outD, outT, outC);
}